// Round 9
// baseline (1156.976 us; speedup 1.0000x reference)
//
#include <hip/hip_runtime.h>

#define NN 100000
#define NE 1600000
#define DIM0 11
#define H 128
#define NL 4
#define NG 4096
#define EPS 1e-5f

#define NBKT 98        // buckets of 1024 nodes: bucket = dst >> 10
#define CAP 18432      // fixed bucket capacity (mean 16384, sigma 127 -> 16 sigma)
#define EPB 4096       // edges per block in scatter phase
static constexpr int NBB = (NE + EPB - 1) / EPB;  // 391

typedef _Float16 f16x8 __attribute__((ext_vector_type(8)));
typedef _Float16 f16x2 __attribute__((ext_vector_type(2)));
typedef float f32x4 __attribute__((ext_vector_type(4)));

// hh/ags live in 8 column-panels of 16 cols: addr = ((panel*NN + node)*16 + c_in_panel).
// Panel = 3.2 MB < 4 MiB per-XCD L2; k_agg3 pins panel = blockIdx&7 so (on the
// round-robin blockIdx->XCD mapping) each XCD's random gathers stay inside its
// own L2-resident panel. r8 evidence: FETCH 196MB = 8 XCDs x full 25.6MB hh copy.

// ---------------- init ----------------

__global__ void k_init(int* __restrict__ bfill, int* __restrict__ gstart, int* __restrict__ gend) {
    int i = blockIdx.x * 256 + threadIdx.x;
    if (i <= NBKT) bfill[i] = 0;
    if (i < NG) { gstart[i] = 0x7fffffff; gend[i] = 0; }
}

// ---------------- bucketed CSR build ----------------

__global__ __launch_bounds__(256) void k_bscatter(const int* __restrict__ src, const int* __restrict__ dst,
                                                  int* __restrict__ bfill, unsigned int* __restrict__ ebuf) {
    __shared__ int lc[NBKT];
    __shared__ int lbase[NBKT];
    int t = threadIdx.x;
    for (int i = t; i < NBKT; i += 256) lc[i] = 0;
    __syncthreads();
    int base = blockIdx.x * EPB;
    int rank[16];
    int bk[16];
    unsigned pk[16];
#pragma unroll
    for (int i = 0; i < 16; i++) {
        int e = base + i * 256 + t;
        if (e < NE) {
            int d = dst[e];
            int s = src[e];
            int b = d >> 10;
            bk[i] = b;
            pk[i] = (unsigned)s | ((unsigned)(d & 1023) << 17);
            rank[i] = atomicAdd(&lc[b], 1);
        } else bk[i] = -1;
    }
    __syncthreads();
    for (int i = t; i < NBKT; i += 256)
        lbase[i] = i * CAP + (lc[i] ? atomicAdd(&bfill[i], lc[i]) : 0);
    __syncthreads();
#pragma unroll
    for (int i = 0; i < 16; i++) {
        if (bk[i] >= 0)
            ebuf[lbase[bk[i]] + rank[i]] = pk[i];
    }
}

__global__ __launch_bounds__(256) void k_bcsr(const unsigned int* __restrict__ ebuf,
                                              const int* __restrict__ bfill,
                                              int* __restrict__ rps, int* __restrict__ rpe,
                                              int* __restrict__ col, float* __restrict__ dis) {
    __shared__ int lcnt[1024];
    __shared__ int lfill[1024];
    __shared__ int tsc[256];
    int t = threadIdx.x;
    int b = blockIdx.x;
    int cb = b * CAP;
    int ecnt = bfill[b];
    int n0 = b << 10;
    int nb = min(1024, NN - n0);

    for (int i = t; i < 1024; i += 256) { lcnt[i] = 0; lfill[i] = 0; }
    __syncthreads();

#pragma unroll 4
    for (int i = t; i < ecnt; i += 256) {
        unsigned p = ebuf[cb + i];
        atomicAdd(&lcnt[p >> 17], 1);
    }
    __syncthreads();

    for (int n = t; n < nb; n += 256)
        dis[n0 + n] = rsqrtf((float)(lcnt[n] + 1));

    int v0 = lcnt[4 * t], v1 = lcnt[4 * t + 1], v2 = lcnt[4 * t + 2], v3 = lcnt[4 * t + 3];
    int ts = v0 + v1 + v2 + v3;
    tsc[t] = ts;
    __syncthreads();
    for (int off = 1; off < 256; off <<= 1) {
        int x = (t >= off) ? tsc[t - off] : 0;
        __syncthreads();
        tsc[t] += x;
        __syncthreads();
    }
    int ex = tsc[t] - ts;
    lcnt[4 * t] = ex;
    lcnt[4 * t + 1] = ex + v0;
    lcnt[4 * t + 2] = ex + v0 + v1;
    lcnt[4 * t + 3] = ex + v0 + v1 + v2;
    __syncthreads();

    for (int n = t; n < nb; n += 256) {
        int st = lcnt[n];
        int en = (n + 1 < 1024) ? ((n + 1 < nb) ? lcnt[n + 1] : ecnt) : ecnt;
        rps[n0 + n] = cb + st;
        rpe[n0 + n] = cb + en;
    }
    __syncthreads();

#pragma unroll 4
    for (int i = t; i < ecnt; i += 256) {
        unsigned p = ebuf[cb + i];
        int dl = p >> 17;
        int s = (int)(p & 0x1FFFFu);
        col[cb + lcnt[dl] + atomicAdd(&lfill[dl], 1)] = s;
    }
}

// ---------------- embed: hh = fp16(relu(x @ W_embed + b)), panel layout ----------------
// r8 evidence: old k_embed was 69us from 2B scalar stores + 50K tiny blocks.
// New: 16 threads/node, 8 cols/thread, f16x8 stores, 6250 blocks.

__global__ __launch_bounds__(256) void k_embed(const float* __restrict__ x, const float* __restrict__ W,
                                               const float* __restrict__ b, _Float16* __restrict__ hh) {
    __shared__ float Ws[DIM0 * H];
    __shared__ float bs[H];
    int tid = threadIdx.x;
    for (int i = tid; i < DIM0 * H; i += 256) Ws[i] = W[i];
    if (tid < H) bs[tid] = b[tid];
    __syncthreads();
    int node = blockIdx.x * 16 + (tid >> 4);   // 16 nodes/block
    int l4 = tid & 15;                          // cols l4*8 .. l4*8+7
    float xr[DIM0];
#pragma unroll
    for (int k = 0; k < DIM0; k++) xr[k] = x[(size_t)node * DIM0 + k];
    f16x8 o;
#pragma unroll
    for (int j = 0; j < 8; j++) {
        int c = l4 * 8 + j;
        float acc = bs[c];
#pragma unroll
        for (int k = 0; k < DIM0; k++) acc += xr[k] * Ws[k * H + c];
        o[j] = (_Float16)fmaxf(acc, 0.f);
    }
    // panel layout: panel = l4>>1, half = l4&1
    *(f16x8*)&hh[(((size_t)(l4 >> 1) * NN + node) << 4) + (l4 & 1) * 8] = o;
}

// ---------------- W pack: W[l][k][n] fp32 -> B-fragment-layout fp16 ----------------

__global__ __launch_bounds__(256) void k_wpack(const float* __restrict__ W, _Float16* __restrict__ Wp) {
    int t = blockIdx.x * 256 + threadIdx.x;   // 8192 threads
    int lane = t & 63;
    int idx = t >> 6;          // 0..127
    int nt = idx & 7;
    int ks = (idx >> 3) & 3;
    int l = idx >> 5;
    int q = lane >> 4, l15 = lane & 15;
    const float* Wl = W + (size_t)l * H * H;
    _Float16* o = Wp + (size_t)idx * 512 + lane * 8;
#pragma unroll
    for (int j = 0; j < 8; j++)
        o[j] = (_Float16)(Wl[(ks * 32 + q * 8 + j) * H + nt * 16 + l15]);
}

// ---------------- aggregate (panel-split): ags_p = segsum(norm * hh_p[src]) ----------------
// One wave per (node, panel-of-16-cols). lane: q3 = lane>>3 edge slot, l3 = lane&7
// col pair. Gather = 8 lanes x 4B = 32B/edge, 8 edges per vmem instruction.

__global__ __launch_bounds__(256) void k_agg3(const _Float16* __restrict__ hh, _Float16* __restrict__ ags,
                                              const float* __restrict__ dis, const int* __restrict__ rps,
                                              const int* __restrict__ rpe, const int* __restrict__ col) {
    int tid = threadIdx.x;
    int lane = tid & 63;
    int q3 = lane >> 3;     // edge slot 0..7
    int l3 = lane & 7;      // col pair: 2*l3, 2*l3+1 within the 16-col panel
    int panel = blockIdx.x & 7;
    int node = __builtin_amdgcn_readfirstlane((blockIdx.x >> 3) * 4 + (tid >> 6));

    const f16x2* hp = (const f16x2*)(hh + (((size_t)panel * NN) << 4));  // panel base, f16x2 units

    float dn = dis[node];
    float ax = 0.f, ay = 0.f;
    if (q3 == 0) {  // self-loop counted once
        f16x2 sv = hp[(size_t)node * 8 + l3];
        float ws = dn * dn;
        ax = (float)sv[0] * ws;
        ay = (float)sv[1] * ws;
    }

    int e0 = rps[node], e1 = rpe[node];
    int e = e0 + q3;
    for (; e + 8 < e1; e += 16) {
        int s0 = col[e];
        int s1 = col[e + 8];
        float w0 = dis[s0];
        float w1 = dis[s1];
        f16x2 v0 = hp[(size_t)s0 * 8 + l3];
        f16x2 v1 = hp[(size_t)s1 * 8 + l3];
        w0 *= dn; w1 *= dn;
        ax += (float)v0[0] * w0; ay += (float)v0[1] * w0;
        ax += (float)v1[0] * w1; ay += (float)v1[1] * w1;
    }
    for (; e < e1; e += 8) {
        int s = col[e];
        float w = dis[s] * dn;
        f16x2 v = hp[(size_t)s * 8 + l3];
        ax += (float)v[0] * w;
        ay += (float)v[1] * w;
    }

    // combine the 8 edge slots (xor lane bits 3,4,5)
    ax += __shfl_xor(ax, 8, 64);  ay += __shfl_xor(ay, 8, 64);
    ax += __shfl_xor(ax, 16, 64); ay += __shfl_xor(ay, 16, 64);
    ax += __shfl_xor(ax, 32, 64); ay += __shfl_xor(ay, 32, 64);

    if (q3 == 0) {
        f16x2 o;
        o[0] = (_Float16)ax;
        o[1] = (_Float16)ay;
        ((f16x2*)ags)[(((size_t)panel * NN + node) << 3) + l3] = o;
    }
}

// ---------------- fused GEMM + bias + LN + relu + residual (panel layout) ----------------

__global__ __launch_bounds__(256) void k_gemmf(const _Float16* __restrict__ ags,
                                               const _Float16* __restrict__ Wp,
                                               const float* __restrict__ bias,
                                               const float* __restrict__ gamma,
                                               const float* __restrict__ beta,
                                               _Float16* __restrict__ hh) {
    __shared__ _Float16 Ls[4][16][136];  // row stride 272B, bank-spread
    int tid = threadIdx.x;
    int wave = tid >> 6;
    int lane = tid & 63;
    int q = lane >> 4, l15 = lane & 15;
    int rbase = blockIdx.x * 64 + wave * 16;

    int arow = rbase + l15;
    if (arow >= NN) arow = NN - 1;      // clamp; polluted rows are store-guarded
    f16x8 a[4];
#pragma unroll
    for (int ks = 0; ks < 4; ks++) {
        // cols ks*32 + q*8 .. +7 -> panel ks*2 + (q>>1), offset (q&1)*8
        int pan = ks * 2 + (q >> 1);
        a[ks] = *(const f16x8*)&ags[(((size_t)pan * NN + arow) << 4) + (q & 1) * 8];
    }

    float bb[8], gm[8], bt[8];
#pragma unroll
    for (int nt = 0; nt < 8; nt++) {
        bb[nt] = bias[nt * 16 + l15];
        gm[nt] = gamma[nt * 16 + l15];
        bt[nt] = beta[nt * 16 + l15];
    }

    const f16x8* wp8 = (const f16x8*)Wp;
    f32x4 acc[8];
#pragma unroll
    for (int nt = 0; nt < 8; nt++) {
        acc[nt] = (f32x4){0.f, 0.f, 0.f, 0.f};
#pragma unroll
        for (int ks = 0; ks < 4; ks++) {
            f16x8 bf = wp8[(ks * 8 + nt) * 64 + lane];
            acc[nt] = __builtin_amdgcn_mfma_f32_16x16x32_f16(a[ks], bf, acc[nt], 0, 0, 0);
        }
#pragma unroll
        for (int r = 0; r < 4; r++) acc[nt][r] += bb[nt];
    }

    float mu[4], rs[4];
#pragma unroll
    for (int r = 0; r < 4; r++) {
        float s = 0.f;
#pragma unroll
        for (int nt = 0; nt < 8; nt++) s += acc[nt][r];
#pragma unroll
        for (int off = 8; off > 0; off >>= 1) s += __shfl_xor(s, off, 64);
        mu[r] = s * (1.f / 128.f);
    }
#pragma unroll
    for (int r = 0; r < 4; r++) {
        float v = 0.f;
#pragma unroll
        for (int nt = 0; nt < 8; nt++) {
            float d = acc[nt][r] - mu[r];
            v += d * d;
        }
#pragma unroll
        for (int off = 8; off > 0; off >>= 1) v += __shfl_xor(v, off, 64);
        rs[r] = rsqrtf(v * (1.f / 128.f) + EPS);
    }

#pragma unroll
    for (int nt = 0; nt < 8; nt++)
#pragma unroll
        for (int r = 0; r < 4; r++) {
            float o = fmaxf((acc[nt][r] - mu[r]) * rs[r] * gm[nt] + bt[nt], 0.f);
            Ls[wave][q * 4 + r][nt * 16 + l15] = (_Float16)o;
        }

    // epilogue: residual add + store into panel layout
#pragma unroll
    for (int it = 0; it < 4; it++) {
        int c = it * 64 + lane;
        int rr = c >> 4, ck = c & 15;      // ck -> cols ck*8..+7 -> panel ck>>1, half ck&1
        int row = rbase + rr;
        if (row < NN) {
            _Float16* hp = &hh[(((size_t)(ck >> 1) * NN + row) << 4) + (ck & 1) * 8];
            f16x8 ln = *(const f16x8*)&Ls[wave][rr][ck * 8];
            f16x8 res = *(const f16x8*)hp;
            f16x8 o;
#pragma unroll
            for (int j = 0; j < 8; j++) o[j] = (_Float16)((float)ln[j] + (float)res[j]);
            *(f16x8*)hp = o;
        }
    }
}

// ---------------- pooling ----------------

__global__ void k_range(const int* __restrict__ batch, int* __restrict__ gstart, int* __restrict__ gend) {
    int n = blockIdx.x * 256 + threadIdx.x;
    if (n < NN) {
        int g = batch[n];
        atomicMin(&gstart[g], n);
        atomicMax(&gend[g], n + 1);
    }
}

__global__ __launch_bounds__(256) void k_pool(const _Float16* __restrict__ hh, const int* __restrict__ gstart,
                                              const int* __restrict__ gend, const float* __restrict__ Wout,
                                              const float* __restrict__ bout, float* __restrict__ out) {
    int tid = threadIdx.x;
    int lane = tid & 63;
    int p = lane >> 3;      // panel
    int cp = lane & 7;      // col pair within panel
    int g = blockIdx.x * 4 + (tid >> 6);
    if (g >= NG) return;

    int s = gstart[g], e = gend[g];
    const f16x2* hp = (const f16x2*)hh;
    size_t pbase = ((size_t)p * NN) << 3;
    float axx = 0.f, ayy = 0.f;
    if (s < e) {
        for (int n = s; n < e; n++) {
            f16x2 v = hp[pbase + ((size_t)n << 3) + cp];
            axx += (float)v[0];
            ayy += (float)v[1];
        }
        float inv = 1.f / (float)(e - s);
        axx *= inv;
        ayy *= inv;
    }
    float2 w = ((const float2*)Wout)[lane];   // cols 2*lane, 2*lane+1 == panel p, pair cp
    float pp = axx * w.x + ayy * w.y;
#pragma unroll
    for (int off = 32; off > 0; off >>= 1) pp += __shfl_xor(pp, off, 64);
    if (lane == 0) out[g] = pp + bout[0];
}

// ---------------- launcher ----------------

extern "C" void kernel_launch(void* const* d_in, const int* in_sizes, int n_in,
                              void* d_out, int out_size, void* d_ws, size_t ws_size,
                              hipStream_t stream) {
    const float* x       = (const float*)d_in[0];
    const int*   edge    = (const int*)d_in[1];
    const int*   batch   = (const int*)d_in[2];
    const float* W_embed = (const float*)d_in[3];
    const float* b_embed = (const float*)d_in[4];
    const float* W_gnn   = (const float*)d_in[5];
    const float* b_gnn   = (const float*)d_in[6];
    const float* gamma   = (const float*)d_in[7];
    const float* beta    = (const float*)d_in[8];
    const float* W_out   = (const float*)d_in[9];
    const float* b_out   = (const float*)d_in[10];
    float* out = (float*)d_out;

    char* ws = (char*)d_ws;
    size_t off = 0;
    auto alloc = [&](size_t bytes) -> char* {
        char* p = ws + off;
        off += (bytes + 255) & ~(size_t)255;
        return p;
    };
    _Float16*     hh   = (_Float16*)alloc((size_t)NN * H * 2);
    _Float16*     ags  = (_Float16*)alloc((size_t)NN * H * 2);
    _Float16*     Wp   = (_Float16*)alloc((size_t)NL * 4 * 8 * 512 * 2);
    float*        dis  = (float*)alloc((size_t)NN * 4);
    int*          rps  = (int*)alloc((size_t)NN * 4);
    int*          rpe  = (int*)alloc((size_t)NN * 4);
    int*          col  = (int*)alloc((size_t)NBKT * CAP * 4);
    unsigned int* ebuf = (unsigned int*)alloc((size_t)NBKT * CAP * 4);
    int*          bfill = (int*)alloc((NBKT + 1) * 4);
    int*   gstart = (int*)alloc((size_t)NG * 4);
    int*   gend   = (int*)alloc((size_t)NG * 4);

    const int* srcp = edge;
    const int* dstp = edge + NE;

    k_init<<<(NG + 255) / 256, 256, 0, stream>>>(bfill, gstart, gend);
    k_bscatter<<<NBB, 256, 0, stream>>>(srcp, dstp, bfill, ebuf);
    k_bcsr<<<NBKT, 256, 0, stream>>>(ebuf, bfill, rps, rpe, col, dis);

    k_wpack<<<32, 256, 0, stream>>>(W_gnn, Wp);
    k_embed<<<NN / 16, 256, 0, stream>>>(x, W_embed, b_embed, hh);

    for (int l = 0; l < NL; l++) {
        k_agg3<<<(NN / 4) * 8, 256, 0, stream>>>(hh, ags, dis, rps, rpe, col);
        k_gemmf<<<(NN + 63) / 64, 256, 0, stream>>>(ags, Wp + (size_t)l * 4 * 8 * 512,
                                                    b_gnn + l * H, gamma + l * H, beta + l * H, hh);
    }

    k_range<<<(NN + 255) / 256, 256, 0, stream>>>(batch, gstart, gend);
    k_pool<<<NG / 4, 256, 0, stream>>>(hh, gstart, gend, W_out, b_out, out);
}

// Round 10
// 519.507 us; speedup vs baseline: 2.2271x; 2.2271x over previous
//
#include <hip/hip_runtime.h>

#define NN 100000
#define NE 1600000
#define DIM0 11
#define H 128
#define NL 4
#define NG 4096
#define EPS 1e-5f

#define NBKT 98        // buckets of 1024 nodes: bucket = dst >> 10
#define CAP 18432      // fixed bucket capacity (mean 16384, sigma 127 -> 16 sigma)
#define EPB 4096       // edges per block in scatter phase
static constexpr int NBB = (NE + EPB - 1) / EPB;  // 391

typedef _Float16 f16x8 __attribute__((ext_vector_type(8)));
typedef _Float16 f16x2 __attribute__((ext_vector_type(2)));
typedef float f32x4 __attribute__((ext_vector_type(4)));

// r9 lesson: panel-splitting the gather cut FETCH 3x but multiplied edge-loop
// instructions 8x (235us vs 65us). Row-major 256B rows + wave-per-node is the
// established floor (~65us, 196MB fetch = 8 XCDs x one hh copy, fabric random-
// line ceiling). This round: r8 pipeline + fast embed.

// ---------------- init ----------------

__global__ void k_init(int* __restrict__ bfill, int* __restrict__ gstart, int* __restrict__ gend) {
    int i = blockIdx.x * 256 + threadIdx.x;
    if (i <= NBKT) bfill[i] = 0;
    if (i < NG) { gstart[i] = 0x7fffffff; gend[i] = 0; }
}

// ---------------- bucketed CSR build ----------------

__global__ __launch_bounds__(256) void k_bscatter(const int* __restrict__ src, const int* __restrict__ dst,
                                                  int* __restrict__ bfill, unsigned int* __restrict__ ebuf) {
    __shared__ int lc[NBKT];
    __shared__ int lbase[NBKT];
    int t = threadIdx.x;
    for (int i = t; i < NBKT; i += 256) lc[i] = 0;
    __syncthreads();
    int base = blockIdx.x * EPB;
    int rank[16];
    int bk[16];
    unsigned pk[16];
#pragma unroll
    for (int i = 0; i < 16; i++) {
        int e = base + i * 256 + t;
        if (e < NE) {
            int d = dst[e];
            int s = src[e];
            int b = d >> 10;
            bk[i] = b;
            pk[i] = (unsigned)s | ((unsigned)(d & 1023) << 17);
            rank[i] = atomicAdd(&lc[b], 1);
        } else bk[i] = -1;
    }
    __syncthreads();
    for (int i = t; i < NBKT; i += 256)
        lbase[i] = i * CAP + (lc[i] ? atomicAdd(&bfill[i], lc[i]) : 0);
    __syncthreads();
#pragma unroll
    for (int i = 0; i < 16; i++) {
        if (bk[i] >= 0)
            ebuf[lbase[bk[i]] + rank[i]] = pk[i];
    }
}

__global__ __launch_bounds__(256) void k_bcsr(const unsigned int* __restrict__ ebuf,
                                              const int* __restrict__ bfill,
                                              int* __restrict__ rps, int* __restrict__ rpe,
                                              int* __restrict__ col, float* __restrict__ dis) {
    __shared__ int lcnt[1024];
    __shared__ int lfill[1024];
    __shared__ int tsc[256];
    int t = threadIdx.x;
    int b = blockIdx.x;
    int cb = b * CAP;
    int ecnt = bfill[b];
    int n0 = b << 10;
    int nb = min(1024, NN - n0);

    for (int i = t; i < 1024; i += 256) { lcnt[i] = 0; lfill[i] = 0; }
    __syncthreads();

#pragma unroll 4
    for (int i = t; i < ecnt; i += 256) {
        unsigned p = ebuf[cb + i];
        atomicAdd(&lcnt[p >> 17], 1);
    }
    __syncthreads();

    for (int n = t; n < nb; n += 256)
        dis[n0 + n] = rsqrtf((float)(lcnt[n] + 1));

    int v0 = lcnt[4 * t], v1 = lcnt[4 * t + 1], v2 = lcnt[4 * t + 2], v3 = lcnt[4 * t + 3];
    int ts = v0 + v1 + v2 + v3;
    tsc[t] = ts;
    __syncthreads();
    for (int off = 1; off < 256; off <<= 1) {
        int x = (t >= off) ? tsc[t - off] : 0;
        __syncthreads();
        tsc[t] += x;
        __syncthreads();
    }
    int ex = tsc[t] - ts;
    lcnt[4 * t] = ex;
    lcnt[4 * t + 1] = ex + v0;
    lcnt[4 * t + 2] = ex + v0 + v1;
    lcnt[4 * t + 3] = ex + v0 + v1 + v2;
    __syncthreads();

    for (int n = t; n < nb; n += 256) {
        int st = lcnt[n];
        int en = (n + 1 < 1024) ? ((n + 1 < nb) ? lcnt[n + 1] : ecnt) : ecnt;
        rps[n0 + n] = cb + st;
        rpe[n0 + n] = cb + en;
    }
    __syncthreads();

#pragma unroll 4
    for (int i = t; i < ecnt; i += 256) {
        unsigned p = ebuf[cb + i];
        int dl = p >> 17;
        int s = (int)(p & 0x1FFFFu);
        col[cb + lcnt[dl] + atomicAdd(&lfill[dl], 1)] = s;
    }
}

// ---------------- embed: hh = fp16(relu(x @ W_embed + b)), row-major ----------------
// r8 evidence: old embed = 69us (50K blocks x 5.6KB W staging = 280MB L2 traffic,
// 2B scalar stores). New: 6250 blocks of 16 nodes, x staged in LDS, f16x8 stores.

__global__ __launch_bounds__(256) void k_embed(const float* __restrict__ x, const float* __restrict__ W,
                                               const float* __restrict__ b, _Float16* __restrict__ hh) {
    __shared__ float Ws[DIM0 * H];
    __shared__ float bs[H];
    __shared__ float xs[16 * DIM0];
    int tid = threadIdx.x;
    for (int i = tid; i < DIM0 * H; i += 256) Ws[i] = W[i];
    if (tid < H) bs[tid] = b[tid];
    if (tid < 16 * DIM0) xs[tid] = x[(size_t)blockIdx.x * (16 * DIM0) + tid];
    __syncthreads();
    int nl = tid >> 4;                          // node within block (0..15)
    int node = blockIdx.x * 16 + nl;
    int l4 = tid & 15;                          // cols l4*8 .. l4*8+7
    f16x8 o;
#pragma unroll
    for (int j = 0; j < 8; j++) {
        int c = l4 * 8 + j;
        float acc = bs[c];
#pragma unroll
        for (int k = 0; k < DIM0; k++) acc += xs[nl * DIM0 + k] * Ws[k * H + c];
        o[j] = (_Float16)fmaxf(acc, 0.f);
    }
    *(f16x8*)&hh[(size_t)node * H + l4 * 8] = o;
}

// ---------------- W pack: W[l][k][n] fp32 -> B-fragment-layout fp16 ----------------

__global__ __launch_bounds__(256) void k_wpack(const float* __restrict__ W, _Float16* __restrict__ Wp) {
    int t = blockIdx.x * 256 + threadIdx.x;   // 8192 threads
    int lane = t & 63;
    int idx = t >> 6;          // 0..127
    int nt = idx & 7;
    int ks = (idx >> 3) & 3;
    int l = idx >> 5;
    int q = lane >> 4, l15 = lane & 15;
    const float* Wl = W + (size_t)l * H * H;
    _Float16* o = Wp + (size_t)idx * 512 + lane * 8;
#pragma unroll
    for (int j = 0; j < 8; j++)
        o[j] = (_Float16)(Wl[(ks * 32 + q * 8 + j) * H + nt * 16 + l15]);
}

// ---------------- aggregate only: ags = segsum(norm * hh[src]) + dn^2 * hh ----------------
// Row-major 256B rows; wave per node; 16B/lane gathers = 4 rows per vmem instr,
// 16 edges (4KB) in flight per wave. Established floor: ~65us, FETCH 196MB.

__global__ __launch_bounds__(256) void k_agg2(const _Float16* __restrict__ hh, _Float16* __restrict__ ags,
                                              const float* __restrict__ dis, const int* __restrict__ rps,
                                              const int* __restrict__ rpe, const int* __restrict__ col) {
    int tid = threadIdx.x;
    int lane = tid & 63;
    int q = lane >> 4;      // edge slot within gather group
    int l4 = lane & 15;     // cols 8*l4 .. 8*l4+7
    int node = __builtin_amdgcn_readfirstlane(blockIdx.x * 4 + (tid >> 6));
    if (node >= NN) return;

    const f16x8* h8 = (const f16x8*)hh;

    float dn = dis[node];
    float a[8];
#pragma unroll
    for (int j = 0; j < 8; j++) a[j] = 0.f;
    if (q == 0) {  // self-loop counted once
        f16x8 sv = h8[(size_t)node * 16 + l4];
        float ws = dn * dn;
#pragma unroll
        for (int j = 0; j < 8; j++) a[j] = (float)sv[j] * ws;
    }

    int e0 = rps[node], e1 = rpe[node];
    int e = e0 + q;
    for (; e + 12 < e1; e += 16) {
        int s0 = col[e];
        int s1 = col[e + 4];
        int s2 = col[e + 8];
        int s3 = col[e + 12];
        float w0 = dis[s0];
        float w1 = dis[s1];
        float w2 = dis[s2];
        float w3 = dis[s3];
        f16x8 v0 = h8[(size_t)s0 * 16 + l4];
        f16x8 v1 = h8[(size_t)s1 * 16 + l4];
        f16x8 v2 = h8[(size_t)s2 * 16 + l4];
        f16x8 v3 = h8[(size_t)s3 * 16 + l4];
        w0 *= dn; w1 *= dn; w2 *= dn; w3 *= dn;
#pragma unroll
        for (int j = 0; j < 8; j++) {
            a[j] += (float)v0[j] * w0;
            a[j] += (float)v1[j] * w1;
            a[j] += (float)v2[j] * w2;
            a[j] += (float)v3[j] * w3;
        }
    }
    for (; e < e1; e += 4) {
        int s = col[e];
        float w = dis[s] * dn;
        f16x8 v = h8[(size_t)s * 16 + l4];
#pragma unroll
        for (int j = 0; j < 8; j++) a[j] += (float)v[j] * w;
    }

    // combine the 4 edge-slot quarters
#pragma unroll
    for (int j = 0; j < 8; j++) {
        a[j] += __shfl_xor(a[j], 16, 64);
        a[j] += __shfl_xor(a[j], 32, 64);
    }

    if (q == 0) {
        f16x8 o;
#pragma unroll
        for (int j = 0; j < 8; j++) o[j] = (_Float16)a[j];
        ((f16x8*)ags)[(size_t)node * 16 + l4] = o;
    }
}

// ---------------- fused GEMM + bias + LN + relu + residual ----------------

__global__ __launch_bounds__(256) void k_gemmf(const _Float16* __restrict__ ags,
                                               const _Float16* __restrict__ Wp,
                                               const float* __restrict__ bias,
                                               const float* __restrict__ gamma,
                                               const float* __restrict__ beta,
                                               _Float16* __restrict__ hh) {
    __shared__ _Float16 Ls[4][16][136];  // row stride 272B, bank-spread
    int tid = threadIdx.x;
    int wave = tid >> 6;
    int lane = tid & 63;
    int q = lane >> 4, l15 = lane & 15;
    int rbase = blockIdx.x * 64 + wave * 16;

    const f16x8* ag8 = (const f16x8*)ags;
    int arow = rbase + l15;
    if (arow >= NN) arow = NN - 1;      // clamp; polluted rows are store-guarded
    f16x8 a[4];
#pragma unroll
    for (int ks = 0; ks < 4; ks++)
        a[ks] = ag8[(size_t)arow * 16 + ks * 4 + q];

    float bb[8], gm[8], bt[8];
#pragma unroll
    for (int nt = 0; nt < 8; nt++) {
        bb[nt] = bias[nt * 16 + l15];
        gm[nt] = gamma[nt * 16 + l15];
        bt[nt] = beta[nt * 16 + l15];
    }

    const f16x8* wp8 = (const f16x8*)Wp;
    f32x4 acc[8];
#pragma unroll
    for (int nt = 0; nt < 8; nt++) {
        acc[nt] = (f32x4){0.f, 0.f, 0.f, 0.f};
#pragma unroll
        for (int ks = 0; ks < 4; ks++) {
            f16x8 bf = wp8[(ks * 8 + nt) * 64 + lane];
            acc[nt] = __builtin_amdgcn_mfma_f32_16x16x32_f16(a[ks], bf, acc[nt], 0, 0, 0);
        }
#pragma unroll
        for (int r = 0; r < 4; r++) acc[nt][r] += bb[nt];
    }

    float mu[4], rs[4];
#pragma unroll
    for (int r = 0; r < 4; r++) {
        float s = 0.f;
#pragma unroll
        for (int nt = 0; nt < 8; nt++) s += acc[nt][r];
#pragma unroll
        for (int off = 8; off > 0; off >>= 1) s += __shfl_xor(s, off, 64);
        mu[r] = s * (1.f / 128.f);
    }
#pragma unroll
    for (int r = 0; r < 4; r++) {
        float v = 0.f;
#pragma unroll
        for (int nt = 0; nt < 8; nt++) {
            float d = acc[nt][r] - mu[r];
            v += d * d;
        }
#pragma unroll
        for (int off = 8; off > 0; off >>= 1) v += __shfl_xor(v, off, 64);
        rs[r] = rsqrtf(v * (1.f / 128.f) + EPS);
    }

#pragma unroll
    for (int nt = 0; nt < 8; nt++)
#pragma unroll
        for (int r = 0; r < 4; r++) {
            float o = fmaxf((acc[nt][r] - mu[r]) * rs[r] * gm[nt] + bt[nt], 0.f);
            Ls[wave][q * 4 + r][nt * 16 + l15] = (_Float16)o;
        }

    // epilogue: coalesced read from LDS + residual add + store (wave-private region)
    f16x8* hh8 = (f16x8*)hh;
#pragma unroll
    for (int it = 0; it < 4; it++) {
        int c = it * 64 + lane;
        int rr = c >> 4, ck = c & 15;
        int row = rbase + rr;
        if (row < NN) {
            f16x8 ln = *(const f16x8*)&Ls[wave][rr][ck * 8];
            f16x8 res = hh8[(size_t)row * 16 + ck];
            f16x8 o;
#pragma unroll
            for (int j = 0; j < 8; j++) o[j] = (_Float16)((float)ln[j] + (float)res[j]);
            hh8[(size_t)row * 16 + ck] = o;
        }
    }
}

// ---------------- pooling ----------------

__global__ void k_range(const int* __restrict__ batch, int* __restrict__ gstart, int* __restrict__ gend) {
    int n = blockIdx.x * 256 + threadIdx.x;
    if (n < NN) {
        int g = batch[n];
        atomicMin(&gstart[g], n);
        atomicMax(&gend[g], n + 1);
    }
}

__global__ __launch_bounds__(256) void k_pool(const _Float16* __restrict__ hh, const int* __restrict__ gstart,
                                              const int* __restrict__ gend, const float* __restrict__ Wout,
                                              const float* __restrict__ bout, float* __restrict__ out) {
    int tid = threadIdx.x;
    int lane = tid & 63;
    int g = blockIdx.x * 4 + (tid >> 6);
    if (g >= NG) return;

    int s = gstart[g], e = gend[g];
    const f16x2* h2 = (const f16x2*)hh;
    float axx = 0.f, ayy = 0.f;
    if (s < e) {
        for (int n = s; n < e; n++) {
            f16x2 v = h2[(size_t)n * 64 + lane];
            axx += (float)v[0];
            ayy += (float)v[1];
        }
        float inv = 1.f / (float)(e - s);
        axx *= inv;
        ayy *= inv;
    }
    float2 w = ((const float2*)Wout)[lane];
    float p = axx * w.x + ayy * w.y;
#pragma unroll
    for (int off = 32; off > 0; off >>= 1) p += __shfl_xor(p, off, 64);
    if (lane == 0) out[g] = p + bout[0];
}

// ---------------- launcher ----------------

extern "C" void kernel_launch(void* const* d_in, const int* in_sizes, int n_in,
                              void* d_out, int out_size, void* d_ws, size_t ws_size,
                              hipStream_t stream) {
    const float* x       = (const float*)d_in[0];
    const int*   edge    = (const int*)d_in[1];
    const int*   batch   = (const int*)d_in[2];
    const float* W_embed = (const float*)d_in[3];
    const float* b_embed = (const float*)d_in[4];
    const float* W_gnn   = (const float*)d_in[5];
    const float* b_gnn   = (const float*)d_in[6];
    const float* gamma   = (const float*)d_in[7];
    const float* beta    = (const float*)d_in[8];
    const float* W_out   = (const float*)d_in[9];
    const float* b_out   = (const float*)d_in[10];
    float* out = (float*)d_out;

    char* ws = (char*)d_ws;
    size_t off = 0;
    auto alloc = [&](size_t bytes) -> char* {
        char* p = ws + off;
        off += (bytes + 255) & ~(size_t)255;
        return p;
    };
    _Float16*     hh   = (_Float16*)alloc((size_t)NN * H * 2);
    _Float16*     ags  = (_Float16*)alloc((size_t)NN * H * 2);
    _Float16*     Wp   = (_Float16*)alloc((size_t)NL * 4 * 8 * 512 * 2);
    float*        dis  = (float*)alloc((size_t)NN * 4);
    int*          rps  = (int*)alloc((size_t)NN * 4);
    int*          rpe  = (int*)alloc((size_t)NN * 4);
    int*          col  = (int*)alloc((size_t)NBKT * CAP * 4);
    unsigned int* ebuf = (unsigned int*)alloc((size_t)NBKT * CAP * 4);
    int*          bfill = (int*)alloc((NBKT + 1) * 4);
    int*   gstart = (int*)alloc((size_t)NG * 4);
    int*   gend   = (int*)alloc((size_t)NG * 4);

    const int* srcp = edge;
    const int* dstp = edge + NE;

    k_init<<<(NG + 255) / 256, 256, 0, stream>>>(bfill, gstart, gend);
    k_bscatter<<<NBB, 256, 0, stream>>>(srcp, dstp, bfill, ebuf);
    k_bcsr<<<NBKT, 256, 0, stream>>>(ebuf, bfill, rps, rpe, col, dis);

    k_wpack<<<32, 256, 0, stream>>>(W_gnn, Wp);
    k_embed<<<NN / 16, 256, 0, stream>>>(x, W_embed, b_embed, hh);

    for (int l = 0; l < NL; l++) {
        k_agg2<<<(NN + 3) / 4, 256, 0, stream>>>(hh, ags, dis, rps, rpe, col);
        k_gemmf<<<(NN + 63) / 64, 256, 0, stream>>>(ags, Wp + (size_t)l * 4 * 8 * 512,
                                                    b_gnn + l * H, gamma + l * H, beta + l * H, hh);
    }

    k_range<<<(NN + 255) / 256, 256, 0, stream>>>(batch, gstart, gend);
    k_pool<<<NG / 4, 256, 0, stream>>>(hh, gstart, gend, W_out, b_out, out);
}